// Round 1
// baseline (272.989 us; speedup 1.0000x reference)
//
#include <hip/hip_runtime.h>
#include <hip/hip_bf16.h>

typedef __attribute__((ext_vector_type(8))) short bshort8;      // 8 bf16 (4 VGPR) MFMA frag
typedef __attribute__((ext_vector_type(4))) float f32x4;        // MFMA accumulator
typedef __attribute__((ext_vector_type(4))) float vfloat4;
typedef __attribute__((ext_vector_type(4))) unsigned int vuint4;
typedef __attribute__((ext_vector_type(2))) unsigned int vuint2;

__device__ __forceinline__ unsigned short f2bf(float f) {
    union { float f; unsigned u; } v; v.f = f;
    unsigned u = v.u;
    u += 0x7fffu + ((u >> 16) & 1u);   // round-to-nearest-even
    return (unsigned short)(u >> 16);
}
__device__ __forceinline__ float bf2f(unsigned short h) {
    union { unsigned u; float f; } v; v.u = ((unsigned)h) << 16;
    return v.f;
}

// ---------------------------------------------------------------------------
// Generic C = A[M][K] @ Bt[N][K]^T  (Bt stored [N][K], bf16), MFMA 16x16x32.
// Tile: BM=64, BN=64, BK=32; 4 waves in 2x2; wave tile 32x32 (acc 2x2 frags).
// EPI: 0 = fp32 store, 1 = bf16 store, 2 = exp()->bf16, 3 = *rinv[row]->bf16
// ---------------------------------------------------------------------------
template<int EPI, bool AF32>
__global__ __launch_bounds__(256)
void gemm_bt(const void* __restrict__ Av, const unsigned short* __restrict__ Btv,
             void* __restrict__ Cv, const float* __restrict__ rinvv,
             int M, int N, int K,
             long long aB, long long bB, long long cB, long long rB)
{
    __shared__ __align__(128) char sA[64 * 64];   // 64 rows x 32 bf16 (64B/row)
    __shared__ __align__(128) char sB[64 * 64];

    const int b    = blockIdx.z;
    const int tid  = threadIdx.x;
    const int bRow = blockIdx.y << 6;
    const int bCol = blockIdx.x << 6;
    const int wid  = tid >> 6, lane = tid & 63;
    const int wr   = wid >> 1, wc   = wid & 1;
    const int r16  = lane & 15, kg  = lane >> 4;
    const int srow = tid >> 2,  skc = tid & 3;     // staging: row 0..63, k-chunk 0..3

    const unsigned short* Bt = Btv + (size_t)bB * b;

    f32x4 acc[2][2] = {};

    const size_t aRowBase = (size_t)(bRow + srow) * K + skc * 8;
    const size_t bRowBase = (size_t)(bCol + srow) * K + skc * 8;
    // swizzled LDS byte offset for (row, kchunk): bijective XOR, same fn on R/W
    const unsigned swW = ((((unsigned)srow) << 6) | (((unsigned)skc) << 4))
                         ^ ((((unsigned)srow) & 7u) << 4);

    for (int k0 = 0; k0 < K; k0 += 32) {
        vuint4 apack;
        if constexpr (AF32) {
            const float* ap = (const float*)Av + (size_t)aB * b + aRowBase + k0;
            vfloat4 x0 = *(const vfloat4*)ap;
            vfloat4 x1 = *(const vfloat4*)(ap + 4);
            apack[0] = (unsigned)f2bf(x0[0]) | ((unsigned)f2bf(x0[1]) << 16);
            apack[1] = (unsigned)f2bf(x0[2]) | ((unsigned)f2bf(x0[3]) << 16);
            apack[2] = (unsigned)f2bf(x1[0]) | ((unsigned)f2bf(x1[1]) << 16);
            apack[3] = (unsigned)f2bf(x1[2]) | ((unsigned)f2bf(x1[3]) << 16);
        } else {
            const unsigned short* ap = (const unsigned short*)Av + (size_t)aB * b + aRowBase + k0;
            apack = *(const vuint4*)ap;
        }
        vuint4 bpack = *(const vuint4*)(Bt + bRowBase + k0);
        *(vuint4*)(sA + swW) = apack;
        *(vuint4*)(sB + swW) = bpack;
        __syncthreads();

        bshort8 af[2], bfr[2];
        #pragma unroll
        for (int mi = 0; mi < 2; mi++) {
            unsigned row = (unsigned)(wr * 32 + mi * 16 + r16);
            unsigned off = ((row << 6) | (((unsigned)kg) << 4)) ^ ((row & 7u) << 4);
            af[mi] = *(const bshort8*)(sA + off);
        }
        #pragma unroll
        for (int ni = 0; ni < 2; ni++) {
            unsigned col = (unsigned)(wc * 32 + ni * 16 + r16);
            unsigned off = ((col << 6) | (((unsigned)kg) << 4)) ^ ((col & 7u) << 4);
            bfr[ni] = *(const bshort8*)(sB + off);
        }
        #pragma unroll
        for (int mi = 0; mi < 2; mi++)
            #pragma unroll
            for (int ni = 0; ni < 2; ni++)
                acc[mi][ni] = __builtin_amdgcn_mfma_f32_16x16x32_bf16(
                                  af[mi], bfr[ni], acc[mi][ni], 0, 0, 0);
        __syncthreads();
    }

    // Epilogue. D frag: col = lane&15, row = (lane>>4)*4 + r  [verified layout]
    #pragma unroll
    for (int mi = 0; mi < 2; mi++) {
        const int row0 = bRow + wr * 32 + mi * 16 + kg * 4;
        #pragma unroll
        for (int ni = 0; ni < 2; ni++) {
            const int col = bCol + wc * 32 + ni * 16 + r16;
            #pragma unroll
            for (int r = 0; r < 4; r++) {
                const int row = row0 + r;
                float x = acc[mi][ni][r];
                if constexpr (EPI == 2) x = __expf(x);
                if constexpr (EPI == 3) x *= rinvv[(size_t)rB * b + row];
                const size_t ci = (size_t)cB * b + (size_t)row * N + col;
                if constexpr (EPI == 0) ((float*)Cv)[ci] = x;
                else                    ((unsigned short*)Cv)[ci] = f2bf(x);
            }
        }
    }
}

// 2x2 avgpool NHWC fp32 -> bf16, 4 channels per thread
__global__ __launch_bounds__(256)
void pool2(const float* __restrict__ x, unsigned short* __restrict__ xp)
{
    const int t  = blockIdx.x * 256 + threadIdx.x;   // 8*32*32*128 threads
    const int c4 = t & 127;
    const int j  = (t >> 7) & 31;
    const int i  = (t >> 12) & 31;
    const int b  = t >> 17;
    const float* p = x + ((((size_t)b * 64 + 2 * i) * 64) + 2 * j) * 512 + c4 * 4;
    vfloat4 a0 = *(const vfloat4*)p;
    vfloat4 a1 = *(const vfloat4*)(p + 512);
    vfloat4 a2 = *(const vfloat4*)(p + 64 * 512);
    vfloat4 a3 = *(const vfloat4*)(p + 64 * 512 + 512);
    float r0 = 0.25f * (a0[0] + a1[0] + a2[0] + a3[0]);
    float r1 = 0.25f * (a0[1] + a1[1] + a2[1] + a3[1]);
    float r2 = 0.25f * (a0[2] + a1[2] + a2[2] + a3[2]);
    float r3 = 0.25f * (a0[3] + a1[3] + a2[3] + a3[3]);
    vuint2 o;
    o[0] = (unsigned)f2bf(r0) | ((unsigned)f2bf(r1) << 16);
    o[1] = (unsigned)f2bf(r2) | ((unsigned)f2bf(r3) << 16);
    *(vuint2*)(xp + (size_t)t * 4) = o;
}

// weights: in fp32 [Kdim][Ndim] -> out bf16 [Ndim][Kdim]
__global__ __launch_bounds__(256)
void transpose_cast(const float* __restrict__ in, unsigned short* __restrict__ out,
                    int Kdim, int Ndim)
{
    const int idx = blockIdx.x * 256 + threadIdx.x;
    if (idx >= Kdim * Ndim) return;
    const int n = idx / Kdim, k = idx % Kdim;
    out[idx] = f2bf(in[(size_t)k * Ndim + n]);
}

// h [8][1024][256] bf16 -> ht [8][256][1024] bf16 (LDS 32x32 tiles)
__global__ __launch_bounds__(256)
void transpose_h(const unsigned short* __restrict__ h, unsigned short* __restrict__ ht)
{
    __shared__ unsigned short tile[32][33];
    const int b  = blockIdx.z;
    const int v0 = blockIdx.x * 32, m0 = blockIdx.y * 32;
    const int tx = threadIdx.x & 31, ty = threadIdx.x >> 5;  // ty 0..7
    const unsigned short* hp = h + (size_t)b * 1024 * 256;
    #pragma unroll
    for (int s = 0; s < 4; s++)
        tile[ty + s * 8][tx] = hp[(size_t)(m0 + ty + s * 8) * 256 + v0 + tx];
    __syncthreads();
    unsigned short* op = ht + (size_t)b * 256 * 1024;
    #pragma unroll
    for (int s = 0; s < 4; s++)
        op[(size_t)(v0 + ty + s * 8) * 1024 + m0 + tx] = tile[tx][ty + s * 8];
}

// per-row sum of exp-scores -> reciprocal. P flat [32768][1024] bf16.
__global__ __launch_bounds__(256)
void rowsum_rinv(const unsigned short* __restrict__ P, float* __restrict__ rinv)
{
    const int wid = threadIdx.x >> 6, lane = threadIdx.x & 63;
    const int row = blockIdx.x * 4 + wid;
    const unsigned short* p = P + (size_t)row * 1024 + lane * 16;
    vuint4 v0 = *(const vuint4*)p;
    vuint4 v1 = *(const vuint4*)(p + 8);
    float s = 0.f;
    #pragma unroll
    for (int i = 0; i < 4; i++) {
        unsigned u = v0[i];
        s += bf2f((unsigned short)(u & 0xffff)) + bf2f((unsigned short)(u >> 16));
        u = v1[i];
        s += bf2f((unsigned short)(u & 0xffff)) + bf2f((unsigned short)(u >> 16));
    }
    #pragma unroll
    for (int off = 32; off > 0; off >>= 1) s += __shfl_xor(s, off, 64);
    if (lane == 0) rinv[row] = 1.0f / s;
}

extern "C" void kernel_launch(void* const* d_in, const int* in_sizes, int n_in,
                              void* d_out, int out_size, void* d_ws, size_t ws_size,
                              hipStream_t stream)
{
    const float* x  = (const float*)d_in[0];
    const float* wf = (const float*)d_in[1];
    const float* wg = (const float*)d_in[2];
    const float* wh = (const float*)d_in[3];
    const float* wo = (const float*)d_in[4];
    float* out = (float*)d_out;

    char* ws = (char*)d_ws;
    size_t off = 0;
    auto carve = [&](size_t bytes) {
        char* p = ws + off;
        off = (off + bytes + 255) & ~(size_t)255;
        return p;
    };
    unsigned short* xp   = (unsigned short*)carve(8ll * 1024 * 512 * 2);   // pooled, bf16
    unsigned short* wf_t = (unsigned short*)carve(64 * 512 * 2);
    unsigned short* wg_t = (unsigned short*)carve(64 * 512 * 2);
    unsigned short* wh_t = (unsigned short*)carve(256 * 512 * 2);
    unsigned short* wo_t = (unsigned short*)carve(512 * 256 * 2);
    unsigned short* fb   = (unsigned short*)carve(8ll * 4096 * 64 * 2);    // queries
    unsigned short* gb   = (unsigned short*)carve(8ll * 1024 * 64 * 2);    // keys
    unsigned short* hb   = (unsigned short*)carve(8ll * 1024 * 256 * 2);   // values
    unsigned short* ht   = (unsigned short*)carve(8ll * 256 * 1024 * 2);   // values^T
    unsigned short* P    = (unsigned short*)carve(8ll * 4096 * 1024 * 2);  // exp(scores)
    float*          rinv = (float*)carve(8ll * 4096 * 4);
    unsigned short* yb   = (unsigned short*)carve(8ll * 4096 * 256 * 2);

    // weight prep (transpose + bf16 cast)
    transpose_cast<<<dim3(128),  256, 0, stream>>>(wf, wf_t, 512, 64);
    transpose_cast<<<dim3(128),  256, 0, stream>>>(wg, wg_t, 512, 64);
    transpose_cast<<<dim3(512),  256, 0, stream>>>(wh, wh_t, 512, 256);
    transpose_cast<<<dim3(512),  256, 0, stream>>>(wo, wo_t, 256, 512);

    // pooled map (bf16)
    pool2<<<dim3(4096), 256, 0, stream>>>(x, xp);

    // projections
    gemm_bt<1, true ><<<dim3(1, 512, 1), 256, 0, stream>>>(x,  wf_t, fb, nullptr,
        32768, 64, 512, 0, 0, 0, 0);
    gemm_bt<1, false><<<dim3(1, 128, 1), 256, 0, stream>>>(xp, wg_t, gb, nullptr,
        8192, 64, 512, 0, 0, 0, 0);
    gemm_bt<1, false><<<dim3(4, 128, 1), 256, 0, stream>>>(xp, wh_t, hb, nullptr,
        8192, 256, 512, 0, 0, 0, 0);
    transpose_h<<<dim3(8, 32, 8), 256, 0, stream>>>(hb, ht);

    // attention: P = exp(f @ g^T)   [batched]
    gemm_bt<2, false><<<dim3(16, 64, 8), 256, 0, stream>>>(fb, gb, P, nullptr,
        4096, 1024, 64, 4096LL * 64, 1024LL * 64, 4096LL * 1024, 0);
    rowsum_rinv<<<dim3(8192), 256, 0, stream>>>(P, rinv);

    // y = (P @ h) * rinv   [batched]
    gemm_bt<3, false><<<dim3(4, 64, 8), 256, 0, stream>>>(P, ht, yb, rinv,
        4096, 256, 1024, 4096LL * 1024, 256LL * 1024, 4096LL * 256, 4096LL);

    // out = y @ wo  (fp32 store)
    gemm_bt<0, false><<<dim3(8, 512, 1), 256, 0, stream>>>(yb, wo_t, out, nullptr,
        32768, 512, 256, 0, 0, 0, 0);
}

// Round 3
// 219.856 us; speedup vs baseline: 1.2417x; 1.2417x over previous
//
#include <hip/hip_runtime.h>
#include <hip/hip_bf16.h>

typedef __attribute__((ext_vector_type(8))) short bshort8;      // 8 bf16 (4 VGPR) MFMA frag
typedef __attribute__((ext_vector_type(4))) float f32x4;        // MFMA accumulator
typedef __attribute__((ext_vector_type(4))) float vfloat4;
typedef __attribute__((ext_vector_type(4))) unsigned int vuint4;
typedef __attribute__((ext_vector_type(2))) unsigned int vuint2;

__device__ __forceinline__ unsigned short f2bf(float f) {
    union { float f; unsigned u; } v; v.f = f;
    unsigned u = v.u;
    u += 0x7fffu + ((u >> 16) & 1u);   // round-to-nearest-even
    return (unsigned short)(u >> 16);
}

// ---------------------------------------------------------------------------
// Generic C = A[M][K] @ Bt[N][K]^T  (Bt stored [N][K], bf16), MFMA 16x16x32.
// Tile: BM=64, BN=64, BK=32; 4 waves in 2x2; wave tile 32x32 (acc 2x2 frags).
// EPI: 0 = fp32 store, 1 = bf16 store
// ---------------------------------------------------------------------------
template<int EPI, bool AF32>
__global__ __launch_bounds__(256)
void gemm_bt(const void* __restrict__ Av, const unsigned short* __restrict__ Btv,
             void* __restrict__ Cv,
             int M, int N, int K)
{
    __shared__ __align__(128) char sA[64 * 64];   // 64 rows x 32 bf16 (64B/row)
    __shared__ __align__(128) char sB[64 * 64];

    const int tid  = threadIdx.x;
    const int bRow = blockIdx.y << 6;
    const int bCol = blockIdx.x << 6;
    const int wid  = tid >> 6, lane = tid & 63;
    const int wr   = wid >> 1, wc   = wid & 1;
    const int r16  = lane & 15, kg  = lane >> 4;
    const int srow = tid >> 2,  skc = tid & 3;     // staging: row 0..63, k-chunk 0..3

    f32x4 acc[2][2] = {};

    const size_t aRowBase = (size_t)(bRow + srow) * K + skc * 8;
    const size_t bRowBase = (size_t)(bCol + srow) * K + skc * 8;
    // swizzled LDS byte offset for (row, kchunk): bijective XOR, same fn on R/W
    const unsigned swW = ((((unsigned)srow) << 6) | (((unsigned)skc) << 4))
                         ^ ((((unsigned)srow) & 7u) << 4);

    for (int k0 = 0; k0 < K; k0 += 32) {
        vuint4 apack;
        if constexpr (AF32) {
            const float* ap = (const float*)Av + aRowBase + k0;
            vfloat4 x0 = *(const vfloat4*)ap;
            vfloat4 x1 = *(const vfloat4*)(ap + 4);
            apack[0] = (unsigned)f2bf(x0[0]) | ((unsigned)f2bf(x0[1]) << 16);
            apack[1] = (unsigned)f2bf(x0[2]) | ((unsigned)f2bf(x0[3]) << 16);
            apack[2] = (unsigned)f2bf(x1[0]) | ((unsigned)f2bf(x1[1]) << 16);
            apack[3] = (unsigned)f2bf(x1[2]) | ((unsigned)f2bf(x1[3]) << 16);
        } else {
            const unsigned short* ap = (const unsigned short*)Av + aRowBase + k0;
            apack = *(const vuint4*)ap;
        }
        vuint4 bpack = *(const vuint4*)((const unsigned short*)Btv + bRowBase + k0);
        *(vuint4*)(sA + swW) = apack;
        *(vuint4*)(sB + swW) = bpack;
        __syncthreads();

        bshort8 af[2], bfr[2];
        #pragma unroll
        for (int mi = 0; mi < 2; mi++) {
            unsigned row = (unsigned)(wr * 32 + mi * 16 + r16);
            unsigned off = ((row << 6) | (((unsigned)kg) << 4)) ^ ((row & 7u) << 4);
            af[mi] = *(const bshort8*)(sA + off);
        }
        #pragma unroll
        for (int ni = 0; ni < 2; ni++) {
            unsigned col = (unsigned)(wc * 32 + ni * 16 + r16);
            unsigned off = ((col << 6) | (((unsigned)kg) << 4)) ^ ((col & 7u) << 4);
            bfr[ni] = *(const bshort8*)(sB + off);
        }
        #pragma unroll
        for (int mi = 0; mi < 2; mi++)
            #pragma unroll
            for (int ni = 0; ni < 2; ni++)
                acc[mi][ni] = __builtin_amdgcn_mfma_f32_16x16x32_bf16(
                                  af[mi], bfr[ni], acc[mi][ni], 0, 0, 0);
        __syncthreads();
    }

    // Epilogue. D frag: col = lane&15, row = (lane>>4)*4 + r  [verified layout]
    #pragma unroll
    for (int mi = 0; mi < 2; mi++) {
        const int row0 = bRow + wr * 32 + mi * 16 + kg * 4;
        #pragma unroll
        for (int ni = 0; ni < 2; ni++) {
            const int col = bCol + wc * 32 + ni * 16 + r16;
            #pragma unroll
            for (int r = 0; r < 4; r++) {
                const int row = row0 + r;
                float x = acc[mi][ni][r];
                const size_t ci = (size_t)row * N + col;
                if constexpr (EPI == 0) ((float*)Cv)[ci] = x;
                else                    ((unsigned short*)Cv)[ci] = f2bf(x);
            }
        }
    }
}

// ---------------------------------------------------------------------------
// Flash attention: per block 64 Q-rows of one batch.
//   S = f @ g^T (K=64), P = exp(S), y = (P @ h) / rowsum(P)
// f: [8][4096][64] bf16, g: [8][1024][64] bf16, ht: [8][256][1024] bf16
// y: [8][4096][256] bf16
// 4 waves 2x2. QK wave tile 32q x 32k; PV wave tile 32q x 128n.
// ---------------------------------------------------------------------------
__global__ __launch_bounds__(256)
void flash_attn(const unsigned short* __restrict__ fb,
                const unsigned short* __restrict__ gb,
                const unsigned short* __restrict__ ht,
                unsigned short* __restrict__ yb)
{
    __shared__ __align__(128) char sS[64 * 128];    // f tile, then P tile
    __shared__ __align__(128) char sG[64 * 128];    // g chunk [64 keys][64 d]
    __shared__ __align__(128) char sH[256 * 128];   // ht chunk [256 n][64 k]
    __shared__ float rs[64];

    const int tid = threadIdx.x;
    const int b   = blockIdx.y;
    const int q0  = blockIdx.x << 6;
    const int wid = tid >> 6, lane = tid & 63;
    const int wr  = wid >> 1, wc = wid & 1;
    const int r16 = lane & 15, kg = lane >> 4;

    const unsigned short* fB = fb + ((size_t)b * 4096 + q0) * 64;
    const unsigned short* gB = gb + (size_t)b * 1024 * 64;
    const unsigned short* hB = ht + (size_t)b * 256 * 1024;

    // ---- stage f tile [64 rows][64 d] into sS (swizzled) ----
    {
        const int row = tid >> 2, kc0 = tid & 3;
        #pragma unroll
        for (int it = 0; it < 2; it++) {
            const int kc = kc0 + it * 4;
            vuint4 v = *(const vuint4*)(fB + (size_t)row * 64 + kc * 8);
            unsigned off = ((unsigned)row * 128 + (unsigned)kc * 16) ^ (((unsigned)row & 7u) << 4);
            *(vuint4*)(sS + off) = v;
        }
    }
    __syncthreads();

    // ---- hold f A-frags in registers for the whole kernel ----
    bshort8 af[2][2];
    #pragma unroll
    for (int mi = 0; mi < 2; mi++)
        #pragma unroll
        for (int s = 0; s < 2; s++) {
            unsigned row = (unsigned)(wr * 32 + mi * 16 + r16);
            unsigned off = (row * 128 + (unsigned)s * 64 + (unsigned)kg * 16) ^ ((row & 7u) << 4);
            af[mi][s] = *(const bshort8*)(sS + off);
        }

    f32x4 yacc[2][8] = {};
    float psum[2][4] = {};

    const int kc = tid & 7, n0 = tid >> 3;   // staging coords

    for (int c = 0; c < 16; c++) {
        const int kv0 = c << 6;
        // ---- stage g chunk + h chunk ----
        #pragma unroll
        for (int it = 0; it < 2; it++) {
            const int n = n0 + it * 32;
            vuint4 v = *(const vuint4*)(gB + (size_t)(kv0 + n) * 64 + kc * 8);
            unsigned off = ((unsigned)n * 128 + (unsigned)kc * 16) ^ (((unsigned)n & 7u) << 4);
            *(vuint4*)(sG + off) = v;
        }
        #pragma unroll
        for (int it = 0; it < 8; it++) {
            const int n = n0 + it * 32;
            vuint4 v = *(const vuint4*)(hB + (size_t)n * 1024 + kv0 + kc * 8);
            unsigned off = ((unsigned)n * 128 + (unsigned)kc * 16) ^ (((unsigned)n & 7u) << 4);
            *(vuint4*)(sH + off) = v;
        }
        __syncthreads();   // also protects sS (af reads / previous PV) from P writes below

        // ---- QK: S = f @ g^T ----
        f32x4 sacc[2][2] = {};
        #pragma unroll
        for (int ni = 0; ni < 2; ni++)
            #pragma unroll
            for (int s = 0; s < 2; s++) {
                unsigned col = (unsigned)(wc * 32 + ni * 16 + r16);
                unsigned off = (col * 128 + (unsigned)s * 64 + (unsigned)kg * 16) ^ ((col & 7u) << 4);
                bshort8 g8 = *(const bshort8*)(sG + off);
                #pragma unroll
                for (int mi = 0; mi < 2; mi++)
                    sacc[mi][ni] = __builtin_amdgcn_mfma_f32_16x16x32_bf16(
                                       af[mi][s], g8, sacc[mi][ni], 0, 0, 0);
            }

        // ---- exp, rowsum partials, write P tile to sS ----
        #pragma unroll
        for (int mi = 0; mi < 2; mi++)
            #pragma unroll
            for (int ni = 0; ni < 2; ni++) {
                const unsigned col = (unsigned)(wc * 32 + ni * 16 + r16);
                #pragma unroll
                for (int r = 0; r < 4; r++) {
                    float e = __expf(sacc[mi][ni][r]);
                    psum[mi][r] += e;
                    unsigned row = (unsigned)(wr * 32 + mi * 16 + kg * 4 + r);
                    unsigned off = (row * 128 + col * 2) ^ ((row & 7u) << 4);
                    *(unsigned short*)(sS + off) = f2bf(e);
                }
            }
        __syncthreads();

        // ---- PV: yacc += P @ h ----
        bshort8 pa[2][2];
        #pragma unroll
        for (int mi = 0; mi < 2; mi++)
            #pragma unroll
            for (int s = 0; s < 2; s++) {
                unsigned row = (unsigned)(wr * 32 + mi * 16 + r16);
                unsigned off = (row * 128 + (unsigned)s * 64 + (unsigned)kg * 16) ^ ((row & 7u) << 4);
                pa[mi][s] = *(const bshort8*)(sS + off);
            }
        #pragma unroll
        for (int ni = 0; ni < 8; ni++) {
            unsigned col = (unsigned)(wc * 128 + ni * 16 + r16);
            unsigned base = col * 128;
            unsigned sw = (col & 7u) << 4;
            bshort8 b0 = *(const bshort8*)(sH + ((base + (unsigned)kg * 16) ^ sw));
            bshort8 b1 = *(const bshort8*)(sH + ((base + 64 + (unsigned)kg * 16) ^ sw));
            #pragma unroll
            for (int mi = 0; mi < 2; mi++) {
                yacc[mi][ni] = __builtin_amdgcn_mfma_f32_16x16x32_bf16(pa[mi][0], b0, yacc[mi][ni], 0, 0, 0);
                yacc[mi][ni] = __builtin_amdgcn_mfma_f32_16x16x32_bf16(pa[mi][1], b1, yacc[mi][ni], 0, 0, 0);
            }
        }
        __syncthreads();   // before next chunk overwrites sG/sH (and sS)
    }

    // ---- rowsum: reduce across the 16 lanes of each row-group ----
    #pragma unroll
    for (int mi = 0; mi < 2; mi++)
        #pragma unroll
        for (int r = 0; r < 4; r++) {
            float s = psum[mi][r];
            s += __shfl_xor(s, 1, 64);
            s += __shfl_xor(s, 2, 64);
            s += __shfl_xor(s, 4, 64);
            s += __shfl_xor(s, 8, 64);
            psum[mi][r] = s;
        }
    if (wc == 0 && r16 == 0) {
        #pragma unroll
        for (int mi = 0; mi < 2; mi++)
            #pragma unroll
            for (int r = 0; r < 4; r++)
                rs[wr * 32 + mi * 16 + kg * 4 + r] = psum[mi][r];
    }
    __syncthreads();
    if (wc == 1 && r16 == 0) {
        #pragma unroll
        for (int mi = 0; mi < 2; mi++)
            #pragma unroll
            for (int r = 0; r < 4; r++)
                rs[wr * 32 + mi * 16 + kg * 4 + r] += psum[mi][r];
    }
    __syncthreads();

    // ---- normalize + store y ----
    unsigned short* yB = yb + ((size_t)b * 4096 + q0) * 256;
    #pragma unroll
    for (int mi = 0; mi < 2; mi++)
        #pragma unroll
        for (int r = 0; r < 4; r++) {
            const int row = wr * 32 + mi * 16 + kg * 4 + r;
            const float rinv = 1.0f / rs[row];
            #pragma unroll
            for (int ni = 0; ni < 8; ni++) {
                const int col = wc * 128 + ni * 16 + r16;
                yB[(size_t)row * 256 + col] = f2bf(yacc[mi][ni][r] * rinv);
            }
        }
}

// 2x2 avgpool NHWC fp32 -> bf16, 4 channels per thread
__global__ __launch_bounds__(256)
void pool2(const float* __restrict__ x, unsigned short* __restrict__ xp)
{
    const int t  = blockIdx.x * 256 + threadIdx.x;   // 8*32*32*128 threads
    const int c4 = t & 127;
    const int j  = (t >> 7) & 31;
    const int i  = (t >> 12) & 31;
    const int b  = t >> 17;
    const float* p = x + ((((size_t)b * 64 + 2 * i) * 64) + 2 * j) * 512 + c4 * 4;
    vfloat4 a0 = *(const vfloat4*)p;
    vfloat4 a1 = *(const vfloat4*)(p + 512);
    vfloat4 a2 = *(const vfloat4*)(p + 64 * 512);
    vfloat4 a3 = *(const vfloat4*)(p + 64 * 512 + 512);
    float r0 = 0.25f * (a0[0] + a1[0] + a2[0] + a3[0]);
    float r1 = 0.25f * (a0[1] + a1[1] + a2[1] + a3[1]);
    float r2 = 0.25f * (a0[2] + a1[2] + a2[2] + a3[2]);
    float r3 = 0.25f * (a0[3] + a1[3] + a2[3] + a3[3]);
    vuint2 o;
    o[0] = (unsigned)f2bf(r0) | ((unsigned)f2bf(r1) << 16);
    o[1] = (unsigned)f2bf(r2) | ((unsigned)f2bf(r3) << 16);
    *(vuint2*)(xp + (size_t)t * 4) = o;
}

// weights: in fp32 [Kdim][Ndim] -> out bf16 [Ndim][Kdim]
__global__ __launch_bounds__(256)
void transpose_cast(const float* __restrict__ in, unsigned short* __restrict__ out,
                    int Kdim, int Ndim)
{
    const int idx = blockIdx.x * 256 + threadIdx.x;
    if (idx >= Kdim * Ndim) return;
    const int n = idx / Kdim, k = idx % Kdim;
    out[idx] = f2bf(in[(size_t)k * Ndim + n]);
}

// h [8][1024][256] bf16 -> ht [8][256][1024] bf16 (LDS 32x32 tiles)
__global__ __launch_bounds__(256)
void transpose_h(const unsigned short* __restrict__ h, unsigned short* __restrict__ ht)
{
    __shared__ unsigned short tile[32][33];
    const int b  = blockIdx.z;
    const int v0 = blockIdx.x * 32, m0 = blockIdx.y * 32;
    const int tx = threadIdx.x & 31, ty = threadIdx.x >> 5;  // ty 0..7
    const unsigned short* hp = h + (size_t)b * 1024 * 256;
    #pragma unroll
    for (int s = 0; s < 4; s++)
        tile[ty + s * 8][tx] = hp[(size_t)(m0 + ty + s * 8) * 256 + v0 + tx];
    __syncthreads();
    unsigned short* op = ht + (size_t)b * 256 * 1024;
    #pragma unroll
    for (int s = 0; s < 4; s++)
        op[(size_t)(v0 + ty + s * 8) * 1024 + m0 + tx] = tile[tx][ty + s * 8];
}

extern "C" void kernel_launch(void* const* d_in, const int* in_sizes, int n_in,
                              void* d_out, int out_size, void* d_ws, size_t ws_size,
                              hipStream_t stream)
{
    const float* x  = (const float*)d_in[0];
    const float* wf = (const float*)d_in[1];
    const float* wg = (const float*)d_in[2];
    const float* wh = (const float*)d_in[3];
    const float* wo = (const float*)d_in[4];
    float* out = (float*)d_out;

    char* ws = (char*)d_ws;
    size_t off = 0;
    auto carve = [&](size_t bytes) {
        char* p = ws + off;
        off = (off + bytes + 255) & ~(size_t)255;
        return p;
    };
    unsigned short* xp   = (unsigned short*)carve(8ll * 1024 * 512 * 2);   // pooled, bf16
    unsigned short* wf_t = (unsigned short*)carve(64 * 512 * 2);
    unsigned short* wg_t = (unsigned short*)carve(64 * 512 * 2);
    unsigned short* wh_t = (unsigned short*)carve(256 * 512 * 2);
    unsigned short* wo_t = (unsigned short*)carve(512 * 256 * 2);
    unsigned short* fb   = (unsigned short*)carve(8ll * 4096 * 64 * 2);    // queries
    unsigned short* gb   = (unsigned short*)carve(8ll * 1024 * 64 * 2);    // keys
    unsigned short* hb   = (unsigned short*)carve(8ll * 1024 * 256 * 2);   // values
    unsigned short* ht   = (unsigned short*)carve(8ll * 256 * 1024 * 2);   // values^T
    unsigned short* yb   = (unsigned short*)carve(8ll * 4096 * 256 * 2);

    // weight prep (transpose + bf16 cast)
    transpose_cast<<<dim3(128),  256, 0, stream>>>(wf, wf_t, 512, 64);
    transpose_cast<<<dim3(128),  256, 0, stream>>>(wg, wg_t, 512, 64);
    transpose_cast<<<dim3(512),  256, 0, stream>>>(wh, wh_t, 512, 256);
    transpose_cast<<<dim3(512),  256, 0, stream>>>(wo, wo_t, 256, 512);

    // pooled map (bf16)
    pool2<<<dim3(4096), 256, 0, stream>>>(x, xp);

    // projections
    gemm_bt<1, true ><<<dim3(1, 512, 1), 256, 0, stream>>>(x,  wf_t, fb, 32768, 64, 512);
    gemm_bt<1, false><<<dim3(1, 128, 1), 256, 0, stream>>>(xp, wg_t, gb, 8192, 64, 512);
    gemm_bt<1, false><<<dim3(4, 128, 1), 256, 0, stream>>>(xp, wh_t, hb, 8192, 256, 512);
    transpose_h<<<dim3(8, 32, 8), 256, 0, stream>>>(hb, ht);

    // fused attention: y = softmax(f g^T) h   (per batch)
    flash_attn<<<dim3(64, 8), 256, 0, stream>>>(fb, gb, ht, yb);

    // out = y @ wo  (fp32 store)
    gemm_bt<0, false><<<dim3(8, 512, 1), 256, 0, stream>>>(yb, wo_t, out, 32768, 512, 256);
}